// Round 14
// baseline (114.731 us; speedup 1.0000x reference)
//
#include <hip/hip_runtime.h>
#include <cstdint>
#include <cstddef>

#define NPTS 8192
#define NUM_CLASSES 5
#define XCOLS 10          // 3 coords + batch + feat + 5 seg
#define EPS2 225.0f
#define MIN_PTS 5
#define NGROUPS 10
#define BIGC 0x3fffffff

#define NLCAP 1536        // max nodes per group (expect ~820)
#define EACAP 8192        // per-group eps-pairs u<v (expect ~5.4k)
#define CPAD 64           // per-group edge counters padded 256 B apart
#define NSLICE 8          // row slices per group in k_pairs
#define KR 3              // row strips per lane (3*64*8 = 1536 = NLCAP)
#define ROUNDS 16

// ---------------- setup: pack coords+p2, group, zero edge counters -----------
__global__ void k_setup(const float* __restrict__ x, float4* __restrict__ q,
                        int* __restrict__ grp, unsigned int* __restrict__ gcnt) {
    int i = blockIdx.x * blockDim.x + threadIdx.x;
    if (i < NGROUPS * CPAD) gcnt[i] = 0u;
    if (i >= NPTS) return;
    const float* r = x + (size_t)i * XCOLS;
    float px = r[0], py = r[1], pz = r[2];
    int b = (int)r[3];
    float best = r[5]; int bc = 0;
    #pragma unroll
    for (int c = 1; c < NUM_CLASSES; c++) {
        float v = r[5 + c];
        if (v > best) { best = v; bc = c; }   // strict > keeps first max (jnp.argmax)
    }
    q[i] = make_float4(px, py, pz, px*px + py*py + pz*pz);
    grp[i] = b * NUM_CLASSES + bc;
}

// ---------------- nodes: ordered per-group node list (parallel prefix) -------
__global__ void __launch_bounds__(1024) k_nodes(
        const int* __restrict__ grp, int* __restrict__ nlist_g,
        int* __restrict__ nn_g) {
    __shared__ unsigned long long masks[NPTS / 64];   // 128 words
    __shared__ int pref[NPTS / 64];
    __shared__ int nnS;
    const int g = blockIdx.x;
    const int tid = threadIdx.x, lane = tid & 63, wv = tid >> 6;

    for (int w = wv; w < NPTS / 64; w += 16) {
        int i = w * 64 + lane;
        unsigned long long bm = __ballot(grp[i] == g);
        if (lane == 0) masks[w] = bm;
    }
    __syncthreads();
    if (wv == 0) {                         // 2-chunk scan of 128 popcounts
        int v0 = __popcll(masks[lane]);
        int incl = v0;
        #pragma unroll
        for (int s = 1; s < 64; s <<= 1) {
            int o = __shfl_up(incl, s);
            if (lane >= s) incl += o;
        }
        pref[lane] = incl - v0;
        int tot0 = __shfl(incl, 63);
        int v1 = __popcll(masks[64 + lane]);
        int incl1 = v1;
        #pragma unroll
        for (int s = 1; s < 64; s <<= 1) {
            int o = __shfl_up(incl1, s);
            if (lane >= s) incl1 += o;
        }
        pref[64 + lane] = tot0 + incl1 - v1;
        if (lane == 63) nnS = tot0 + incl1;
    }
    __syncthreads();
    for (int w = wv; w < NPTS / 64; w += 16) {
        int i = w * 64 + lane;
        unsigned long long bm = masks[w];
        if ((bm >> lane) & 1ull) {
            int p = pref[w] + __popcll(bm & ((1ull << lane) - 1ull));
            if (p < NLCAP) nlist_g[g * NLCAP + p] = i;
        }
    }
    if (tid == 0) nn_g[g] = (nnS > NLCAP) ? NLCAP : nnS;
}

// ---------------- pairs: adjacency -> global edges + FULL degrees ------------
// grid = 10*8; block 256 (4 waves). Wave wq owns chunks c==wq (mod 4); lane
// owns rows s+8*(lane+64k). Full-row popc (self + both triangles) -> complete
// degree at exit; emission masked to v>u. Dead strips (s+512k >= nn) skipped.
__global__ void __launch_bounds__(256) k_pairs(
        const float4* __restrict__ q, const int* __restrict__ nlist_g,
        const int* __restrict__ nn_g, unsigned int* __restrict__ eAll_g,
        unsigned int* __restrict__ gcnt, int* __restrict__ deg_g) {
    __shared__ float4 pts[NLCAP];          // 24 KB
    __shared__ int srowdeg[NLCAP / NSLICE];// 192 rows this slice
    const int g = blockIdx.x / NSLICE;
    const int s = blockIdx.x % NSLICE;
    const int tid = threadIdx.x, lane = tid & 63, wq = tid >> 6;
    const int nn = nn_g[g];

    for (int k = tid; k < NLCAP; k += 256)
        pts[k] = (k < nn) ? q[nlist_g[g * NLCAP + k]]
                          : make_float4(0.f, 0.f, 0.f, 3.0e38f);
    for (int m = tid; m < NLCAP / NSLICE; m += 256) srowdeg[m] = 0;
    __syncthreads();

    int rrow[KR]; float4 qu[KR]; int rowdeg[KR];
    #pragma unroll
    for (int k = 0; k < KR; k++) {
        rrow[k] = s + 8 * (lane + 64 * k);           // < 1536
        qu[k] = pts[rrow[k]];                        // sentinel-safe
        rowdeg[k] = 0;
    }

    const int NC = (nn + 31) >> 5;
    unsigned int* eg = eAll_g + (size_t)g * EACAP;
    for (int c = wq; c < NC; c += 4) {
        int base = c << 5;
        unsigned int bits[KR];
        #pragma unroll
        for (int k = 0; k < KR; k++) bits[k] = 0u;
        #pragma unroll
        for (int t = 0; t < 32; t++) {
            float4 qv = pts[base + t];               // wave-uniform broadcast
            #pragma unroll
            for (int k = 0; k < KR; k++) {
                if (s + 512 * k < nn) {              // uniform strip guard
                    float d2 = qu[k].w + qv.w - 2.0f * (qu[k].x*qv.x + qu[k].y*qv.y + qu[k].z*qv.z);
                    bits[k] |= (d2 < EPS2) ? (1u << t) : 0u;
                }
            }
        }
        int cnt = 0;
        #pragma unroll
        for (int k = 0; k < KR; k++) {
            if (s + 512 * k < nn) {
                rowdeg[k] += __popc(bits[k]);        // FULL adjacency (incl self)
                int d = rrow[k] - base;              // emission: keep v > u
                if (d >= 31) bits[k] = 0u;
                else if (d >= 0) bits[k] &= ~((2u << d) - 1u);
                cnt += __popc(bits[k]);
            }
        }
        int incl = cnt;
        #pragma unroll
        for (int st = 1; st < 64; st <<= 1) {
            int o = __shfl_up(incl, st);
            if (lane >= st) incl += o;
        }
        int tot = __shfl(incl, 63);
        if (tot > 0) {
            unsigned int rbase = 0;
            if (lane == 63) rbase = atomicAdd(&gcnt[g * CPAD], (unsigned int)tot);
            rbase = __shfl(rbase, 63);
            unsigned int p = rbase + (unsigned int)(incl - cnt);
            #pragma unroll
            for (int k = 0; k < KR; k++) {
                if (s + 512 * k < nn) {
                    unsigned int b = bits[k];
                    unsigned int uhi = (unsigned int)rrow[k] << 11;
                    while (b) {
                        int t = __ffs(b) - 1; b &= b - 1;
                        if (p < EACAP) eg[p] = uhi | (unsigned int)(base + t);
                        p++;
                    }
                }
            }
        }
    }
    #pragma unroll
    for (int k = 0; k < KR; k++)
        if (rowdeg[k] > 0) atomicAdd(&srowdeg[lane + 64 * k], rowdeg[k]);
    __syncthreads();
    // unique owner of rows r==s (mod 8): plain store (full degree, self incl.)
    for (int m = tid; m < NLCAP / NSLICE; m += 256)
        deg_g[g * NLCAP + s + 8 * m] = srowdeg[m];
}

// ---------------- graph: core -> SV (gated) -> rank -> border -> output ------
__global__ void __launch_bounds__(1024) k_graph(
        const unsigned int* __restrict__ eAll_g, const unsigned int* __restrict__ gcnt,
        const int* __restrict__ deg_g, const int* __restrict__ nlist_g,
        const int* __restrict__ nn_g, const float* __restrict__ x,
        float* __restrict__ out) {
    __shared__ unsigned int eA[EACAP];               // 32 KB
    __shared__ int sdeg[NLCAP];                      // 6 KB -> becomes cid array
    __shared__ int spar[NLCAP];                      // 6 KB
    __shared__ int sbmin[NLCAP];                     // 6 KB
    __shared__ int nlist[NLCAP];                     // 6 KB
    __shared__ unsigned long long corebm[NLCAP/64];  // 192 B
    __shared__ unsigned long long repbm[NLCAP/64];   // 192 B
    __shared__ int flags[ROUNDS];

    const int g = blockIdx.x;
    const int tid = threadIdx.x, lane = tid & 63, wv = tid >> 6;
    const int NN = nn_g[g];
    unsigned int Eu = gcnt[g * CPAD];
    const int NA = (Eu > (unsigned)EACAP) ? EACAP : (int)Eu;

    if (tid < ROUNDS) flags[tid] = 0;
    for (int k = tid; k < NLCAP; k += 1024) {
        sdeg[k] = deg_g[g * NLCAP + k];
        spar[k] = k;
        sbmin[k] = BIGC;
        nlist[k] = nlist_g[g * NLCAP + k];
    }
    for (int e = tid; e < NA; e += 1024) eA[e] = eAll_g[(size_t)g * EACAP + e];
    __syncthreads();
    // core bitmap (degrees already complete)
    for (int w = wv; w < NLCAP / 64; w += 16) {
        int l = w * 64 + lane;
        bool isc = (l < NN) && (sdeg[l] >= MIN_PTS);
        unsigned long long bm = __ballot(isc);
        if (lane == 0) corebm[w] = bm;
    }
    __syncthreads();
    auto corebit = [&](int l) -> bool { return (corebm[l >> 6] >> (l & 63)) & 1ull; };

    // SV rounds: corebit-gated hook-to-min over eA + double pointer jump
    for (int r = 0; r < ROUNDS; r++) {
        for (int k = tid; k < NA; k += 1024) {
            unsigned int pk = eA[k];
            int u = (int)(pk >> 11), v = (int)(pk & 2047u);
            if (corebit(u) && corebit(v)) {
                int a = spar[u], b2 = spar[v];
                if (a < b2)      { int old = atomicMin(&spar[v], a);  if (old > a)  flags[r] = 1; }
                else if (b2 < a) { int old = atomicMin(&spar[u], b2); if (old > b2) flags[r] = 1; }
            }
        }
        __syncthreads();
        for (int k = tid; k < NN; k += 1024) {
            int s = spar[k]; int s2 = spar[s];
            if (s2 < s) { s = spar[s2]; spar[k] = (s < s2) ? s : s2; flags[r] = 1; }
        }
        __syncthreads();
        if (!flags[r]) break;
    }

    // reps + rank into sdeg (degrees dead now); wave 0 serial over 24 words
    for (int w = wv; w < NLCAP / 64; w += 16) {
        int l = w * 64 + lane;
        bool isr = (l < NN) && corebit(l) && (spar[l] == l);
        unsigned long long bm = __ballot(isr);
        if (lane == 0) repbm[w] = bm;
    }
    __syncthreads();
    if (wv == 0) {
        int running = 0;
        for (int w = 0; w < NLCAP / 64; w++) {
            unsigned long long bm = repbm[w];
            if ((bm >> lane) & 1ull)
                sdeg[w * 64 + lane] = running + __popcll(bm & ((1ull << lane) - 1ull));
            running += __popcll(bm);
        }
    }
    __syncthreads();
    // ccid -> overwrite spar
    int cc[2];
    #pragma unroll
    for (int t = 0; t < 2; t++) {
        int k = tid + t * 1024;
        cc[t] = (k < NN && corebit(k)) ? sdeg[spar[k]] : BIGC;
    }
    __syncthreads();
    #pragma unroll
    for (int t = 0; t < 2; t++) {
        int k = tid + t * 1024;
        if (k < NN) spar[k] = cc[t];
    }
    __syncthreads();
    // border: min adjacent core cid for the non-core endpoint (over eA)
    for (int k = tid; k < NA; k += 1024) {
        unsigned int pk = eA[k];
        int u = (int)(pk >> 11), v = (int)(pk & 2047u);
        int cu = spar[u], cv = spar[v];
        if (cu == BIGC) { if (cv != BIGC) atomicMin(&sbmin[u], cv); }
        else if (cv == BIGC) atomicMin(&sbmin[v], cu);
    }
    __syncthreads();
    // final labels + clustered output
    for (int k = tid; k < NN; k += 1024) {
        int i = nlist[k];
        int c = spar[k];
        int lbl = (c != BIGC) ? c : ((sbmin[k] < BIGC) ? sbmin[k] : -1);
        out[i] = (float)lbl;
        const float* r = x + (size_t)i * XCOLS;
        float* o = out + NPTS + (size_t)i * 5;
        bool keep = lbl >= 0;
        #pragma unroll
        for (int c5 = 0; c5 < 5; c5++) o[c5] = keep ? r[c5] : 0.0f;
    }
}

extern "C" void kernel_launch(void* const* d_in, const int* in_sizes, int n_in,
                              void* d_out, int out_size, void* d_ws, size_t ws_size,
                              hipStream_t stream) {
    const float* x = (const float*)d_in[0];
    float* out = (float*)d_out;
    char* ws = (char*)d_ws;

    // workspace layout (~660 KB)
    float4* q           = (float4*)(ws);                  // 131072 B
    int* grp            = (int*)(ws + 131072);            // 32768
    unsigned int* gcnt  = (unsigned int*)(ws + 163840);   // 2560
    int* nn_g           = (int*)(ws + 166400);            // 64
    int* nlist_g        = (int*)(ws + 166464);            // 61440
    int* deg_g          = (int*)(ws + 227904);            // 61440
    unsigned int* eAll_g= (unsigned int*)(ws + 289344);   // 327680

    k_setup<<<NPTS / 256, 256, 0, stream>>>(x, q, grp, gcnt);
    k_nodes<<<NGROUPS, 1024, 0, stream>>>(grp, nlist_g, nn_g);
    k_pairs<<<NGROUPS * NSLICE, 256, 0, stream>>>(q, nlist_g, nn_g, eAll_g, gcnt, deg_g);
    k_graph<<<NGROUPS, 1024, 0, stream>>>(eAll_g, gcnt, deg_g, nlist_g, nn_g, x, out);
}

// Round 15
// 112.696 us; speedup vs baseline: 1.0181x; 1.0181x over previous
//
#include <hip/hip_runtime.h>
#include <cstdint>
#include <cstddef>

#define NPTS 8192
#define NUM_CLASSES 5
#define XCOLS 10          // 3 coords + batch + feat + 5 seg
#define EPS2 225.0f
#define MIN_PTS 5
#define NGROUPS 10
#define BIGC 0x3fffffff

#define NLCAP 1536        // max nodes per group (expect ~820)
#define EACAP 8192        // per-group eps-pairs u<v (expect ~5.4k)
#define CPAD 64           // per-group edge counters padded 256 B apart
#define NSLICE 8          // row slices per group in k_pairs
#define KR 3              // row strips per lane (3*64*8 = 1536 = NLCAP)
#define ROUNDS 16

// ---- group id of point i, computed from raw x row (strict > = jnp.argmax) ---
__device__ __forceinline__ int group_of(const float* __restrict__ x, int i) {
    const float* r = x + (size_t)i * XCOLS;
    int b = (int)r[3];
    float best = r[5]; int bc = 0;
    #pragma unroll
    for (int c = 1; c < NUM_CLASSES; c++) {
        float v = r[5 + c];
        if (v > best) { best = v; bc = c; }
    }
    return b * NUM_CLASSES + bc;
}

// ---------------- nodes: ordered per-group node list (parallel prefix) -------
// grp computed inline (x is L2-resident; 10x redundant argmax is trivial).
__global__ void __launch_bounds__(1024) k_nodes(
        const float* __restrict__ x, int* __restrict__ nlist_g,
        int* __restrict__ nn_g, unsigned int* __restrict__ gcnt) {
    __shared__ unsigned long long masks[NPTS / 64];   // 128 words
    __shared__ int pref[NPTS / 64];
    __shared__ int nnS;
    const int g = blockIdx.x;
    const int tid = threadIdx.x, lane = tid & 63, wv = tid >> 6;

    if (tid == 0) gcnt[g * CPAD] = 0u;                // own counter only
    for (int w = wv; w < NPTS / 64; w += 16) {
        int i = w * 64 + lane;
        unsigned long long bm = __ballot(group_of(x, i) == g);
        if (lane == 0) masks[w] = bm;
    }
    __syncthreads();
    if (wv == 0) {                         // 2-chunk scan of 128 popcounts
        int v0 = __popcll(masks[lane]);
        int incl = v0;
        #pragma unroll
        for (int s = 1; s < 64; s <<= 1) {
            int o = __shfl_up(incl, s);
            if (lane >= s) incl += o;
        }
        pref[lane] = incl - v0;
        int tot0 = __shfl(incl, 63);
        int v1 = __popcll(masks[64 + lane]);
        int incl1 = v1;
        #pragma unroll
        for (int s = 1; s < 64; s <<= 1) {
            int o = __shfl_up(incl1, s);
            if (lane >= s) incl1 += o;
        }
        pref[64 + lane] = tot0 + incl1 - v1;
        if (lane == 63) nnS = tot0 + incl1;
    }
    __syncthreads();
    for (int w = wv; w < NPTS / 64; w += 16) {
        int i = w * 64 + lane;
        unsigned long long bm = masks[w];
        if ((bm >> lane) & 1ull) {
            int p = pref[w] + __popcll(bm & ((1ull << lane) - 1ull));
            if (p < NLCAP) nlist_g[g * NLCAP + p] = i;
        }
    }
    if (tid == 0) nn_g[g] = (nnS > NLCAP) ? NLCAP : nnS;
}

// ---------------- pairs: adjacency -> global edges + FULL degrees ------------
// grid = 10*8; block 256 (4 waves). Wave wq owns chunks c==wq (mod 4); lane
// owns rows s+8*(lane+64k). Coords gathered straight from x (p2 inline).
__global__ void __launch_bounds__(256) k_pairs(
        const float* __restrict__ x, const int* __restrict__ nlist_g,
        const int* __restrict__ nn_g, unsigned int* __restrict__ eAll_g,
        unsigned int* __restrict__ gcnt, int* __restrict__ deg_g) {
    __shared__ float4 pts[NLCAP];          // 24 KB
    __shared__ int srowdeg[NLCAP / NSLICE];// 192 rows this slice
    const int g = blockIdx.x / NSLICE;
    const int s = blockIdx.x % NSLICE;
    const int tid = threadIdx.x, lane = tid & 63, wq = tid >> 6;
    const int nn = nn_g[g];

    for (int k = tid; k < NLCAP; k += 256) {
        if (k < nn) {
            const float* r = x + (size_t)nlist_g[g * NLCAP + k] * XCOLS;
            float px = r[0], py = r[1], pz = r[2];
            pts[k] = make_float4(px, py, pz, px*px + py*py + pz*pz);
        } else {
            pts[k] = make_float4(0.f, 0.f, 0.f, 3.0e38f);   // never adjacent
        }
    }
    for (int m = tid; m < NLCAP / NSLICE; m += 256) srowdeg[m] = 0;
    __syncthreads();

    int rrow[KR]; float4 qu[KR]; int rowdeg[KR];
    #pragma unroll
    for (int k = 0; k < KR; k++) {
        rrow[k] = s + 8 * (lane + 64 * k);           // < 1536
        qu[k] = pts[rrow[k]];                        // sentinel-safe
        rowdeg[k] = 0;
    }

    const int NC = (nn + 31) >> 5;
    unsigned int* eg = eAll_g + (size_t)g * EACAP;
    for (int c = wq; c < NC; c += 4) {
        int base = c << 5;
        unsigned int bits[KR];
        #pragma unroll
        for (int k = 0; k < KR; k++) bits[k] = 0u;
        #pragma unroll
        for (int t = 0; t < 32; t++) {
            float4 qv = pts[base + t];               // wave-uniform broadcast
            #pragma unroll
            for (int k = 0; k < KR; k++) {
                if (s + 512 * k < nn) {              // uniform strip guard
                    float d2 = qu[k].w + qv.w - 2.0f * (qu[k].x*qv.x + qu[k].y*qv.y + qu[k].z*qv.z);
                    bits[k] |= (d2 < EPS2) ? (1u << t) : 0u;
                }
            }
        }
        int cnt = 0;
        #pragma unroll
        for (int k = 0; k < KR; k++) {
            if (s + 512 * k < nn) {
                rowdeg[k] += __popc(bits[k]);        // FULL adjacency (incl self)
                int d = rrow[k] - base;              // emission: keep v > u
                if (d >= 31) bits[k] = 0u;
                else if (d >= 0) bits[k] &= ~((2u << d) - 1u);
                cnt += __popc(bits[k]);
            }
        }
        int incl = cnt;
        #pragma unroll
        for (int st = 1; st < 64; st <<= 1) {
            int o = __shfl_up(incl, st);
            if (lane >= st) incl += o;
        }
        int tot = __shfl(incl, 63);
        if (tot > 0) {
            unsigned int rbase = 0;
            if (lane == 63) rbase = atomicAdd(&gcnt[g * CPAD], (unsigned int)tot);
            rbase = __shfl(rbase, 63);
            unsigned int p = rbase + (unsigned int)(incl - cnt);
            #pragma unroll
            for (int k = 0; k < KR; k++) {
                if (s + 512 * k < nn) {
                    unsigned int b = bits[k];
                    unsigned int uhi = (unsigned int)rrow[k] << 11;
                    while (b) {
                        int t = __ffs(b) - 1; b &= b - 1;
                        if (p < EACAP) eg[p] = uhi | (unsigned int)(base + t);
                        p++;
                    }
                }
            }
        }
    }
    #pragma unroll
    for (int k = 0; k < KR; k++)
        if (rowdeg[k] > 0) atomicAdd(&srowdeg[lane + 64 * k], rowdeg[k]);
    __syncthreads();
    // unique owner of rows r==s (mod 8): plain store (full degree, self incl.)
    for (int m = tid; m < NLCAP / NSLICE; m += 256)
        deg_g[g * NLCAP + s + 8 * m] = srowdeg[m];
}

// ---------------- graph: core -> SV (gated) -> rank -> border -> output ------
__global__ void __launch_bounds__(1024) k_graph(
        const unsigned int* __restrict__ eAll_g, const unsigned int* __restrict__ gcnt,
        const int* __restrict__ deg_g, const int* __restrict__ nlist_g,
        const int* __restrict__ nn_g, const float* __restrict__ x,
        float* __restrict__ out) {
    __shared__ unsigned int eA[EACAP];               // 32 KB
    __shared__ int sdeg[NLCAP];                      // 6 KB -> becomes cid array
    __shared__ int spar[NLCAP];                      // 6 KB
    __shared__ int sbmin[NLCAP];                     // 6 KB
    __shared__ int nlist[NLCAP];                     // 6 KB
    __shared__ unsigned long long corebm[NLCAP/64];  // 192 B
    __shared__ unsigned long long repbm[NLCAP/64];   // 192 B
    __shared__ int flags[ROUNDS];

    const int g = blockIdx.x;
    const int tid = threadIdx.x, lane = tid & 63, wv = tid >> 6;
    const int NN = nn_g[g];
    unsigned int Eu = gcnt[g * CPAD];
    const int NA = (Eu > (unsigned)EACAP) ? EACAP : (int)Eu;

    if (tid < ROUNDS) flags[tid] = 0;
    for (int k = tid; k < NLCAP; k += 1024) {
        sdeg[k] = deg_g[g * NLCAP + k];
        spar[k] = k;
        sbmin[k] = BIGC;
        nlist[k] = nlist_g[g * NLCAP + k];
    }
    for (int e = tid; e < NA; e += 1024) eA[e] = eAll_g[(size_t)g * EACAP + e];
    __syncthreads();
    // core bitmap (degrees already complete)
    for (int w = wv; w < NLCAP / 64; w += 16) {
        int l = w * 64 + lane;
        bool isc = (l < NN) && (sdeg[l] >= MIN_PTS);
        unsigned long long bm = __ballot(isc);
        if (lane == 0) corebm[w] = bm;
    }
    __syncthreads();
    auto corebit = [&](int l) -> bool { return (corebm[l >> 6] >> (l & 63)) & 1ull; };

    // SV rounds: corebit-gated hook-to-min over eA + double pointer jump
    for (int r = 0; r < ROUNDS; r++) {
        for (int k = tid; k < NA; k += 1024) {
            unsigned int pk = eA[k];
            int u = (int)(pk >> 11), v = (int)(pk & 2047u);
            if (corebit(u) && corebit(v)) {
                int a = spar[u], b2 = spar[v];
                if (a < b2)      { int old = atomicMin(&spar[v], a);  if (old > a)  flags[r] = 1; }
                else if (b2 < a) { int old = atomicMin(&spar[u], b2); if (old > b2) flags[r] = 1; }
            }
        }
        __syncthreads();
        for (int k = tid; k < NN; k += 1024) {
            int s = spar[k]; int s2 = spar[s];
            if (s2 < s) { s = spar[s2]; spar[k] = (s < s2) ? s : s2; flags[r] = 1; }
        }
        __syncthreads();
        if (!flags[r]) break;
    }

    // reps + rank into sdeg (degrees dead now); wave 0 serial over 24 words
    for (int w = wv; w < NLCAP / 64; w += 16) {
        int l = w * 64 + lane;
        bool isr = (l < NN) && corebit(l) && (spar[l] == l);
        unsigned long long bm = __ballot(isr);
        if (lane == 0) repbm[w] = bm;
    }
    __syncthreads();
    if (wv == 0) {
        int running = 0;
        for (int w = 0; w < NLCAP / 64; w++) {
            unsigned long long bm = repbm[w];
            if ((bm >> lane) & 1ull)
                sdeg[w * 64 + lane] = running + __popcll(bm & ((1ull << lane) - 1ull));
            running += __popcll(bm);
        }
    }
    __syncthreads();
    // ccid -> overwrite spar
    int cc[2];
    #pragma unroll
    for (int t = 0; t < 2; t++) {
        int k = tid + t * 1024;
        cc[t] = (k < NN && corebit(k)) ? sdeg[spar[k]] : BIGC;
    }
    __syncthreads();
    #pragma unroll
    for (int t = 0; t < 2; t++) {
        int k = tid + t * 1024;
        if (k < NN) spar[k] = cc[t];
    }
    __syncthreads();
    // border: min adjacent core cid for the non-core endpoint (over eA)
    for (int k = tid; k < NA; k += 1024) {
        unsigned int pk = eA[k];
        int u = (int)(pk >> 11), v = (int)(pk & 2047u);
        int cu = spar[u], cv = spar[v];
        if (cu == BIGC) { if (cv != BIGC) atomicMin(&sbmin[u], cv); }
        else if (cv == BIGC) atomicMin(&sbmin[v], cu);
    }
    __syncthreads();
    // final labels + clustered output
    for (int k = tid; k < NN; k += 1024) {
        int i = nlist[k];
        int c = spar[k];
        int lbl = (c != BIGC) ? c : ((sbmin[k] < BIGC) ? sbmin[k] : -1);
        out[i] = (float)lbl;
        const float* r = x + (size_t)i * XCOLS;
        float* o = out + NPTS + (size_t)i * 5;
        bool keep = lbl >= 0;
        #pragma unroll
        for (int c5 = 0; c5 < 5; c5++) o[c5] = keep ? r[c5] : 0.0f;
    }
}

extern "C" void kernel_launch(void* const* d_in, const int* in_sizes, int n_in,
                              void* d_out, int out_size, void* d_ws, size_t ws_size,
                              hipStream_t stream) {
    const float* x = (const float*)d_in[0];
    float* out = (float*)d_out;
    char* ws = (char*)d_ws;

    // workspace layout (~460 KB)
    unsigned int* gcnt  = (unsigned int*)(ws);            // 10*64*4 = 2560
    int* nn_g           = (int*)(ws + 2560);              // 64
    int* nlist_g        = (int*)(ws + 2624);              // 10*1536*4 = 61440
    int* deg_g          = (int*)(ws + 64064);             // 61440
    unsigned int* eAll_g= (unsigned int*)(ws + 125504);   // 10*8192*4 = 327680

    k_nodes<<<NGROUPS, 1024, 0, stream>>>(x, nlist_g, nn_g, gcnt);
    k_pairs<<<NGROUPS * NSLICE, 256, 0, stream>>>(x, nlist_g, nn_g, eAll_g, gcnt, deg_g);
    k_graph<<<NGROUPS, 1024, 0, stream>>>(eAll_g, gcnt, deg_g, nlist_g, nn_g, x, out);
}